// Round 10
// baseline (201.031 us; speedup 1.0000x reference)
//
#include <hip/hip_runtime.h>
#include <math.h>

#define T_TOK 2048
#define H_DIM 1024
#define M_DIM 512
#define E_NUM 32
#define TOPK  4

#define MAXT  63            // sum ceil(cnt/256) <= 31 + 8192/256 = 63
#define SLOTS (MAXT * 256)  // 16128 padded pair-slots

typedef __bf16 bf16x8 __attribute__((ext_vector_type(8)));
typedef float f32x4 __attribute__((ext_vector_type(4)));
typedef unsigned short u16x8 __attribute__((ext_vector_type(8)));
typedef unsigned short u16x4 __attribute__((ext_vector_type(4)));

__device__ __forceinline__ unsigned short f2bf(float f) {
  unsigned u = __float_as_uint(f);
  return (unsigned short)((u + 0x7fffu + ((u >> 16) & 1u)) >> 16);
}
__device__ __forceinline__ f32x4 mfma16(bf16x8 a, bf16x8 b, f32x4 c) {
  return __builtin_amdgcn_mfma_f32_16x16x32_bf16(a, b, c, 0, 0, 0);
}
__device__ __forceinline__ void gload16(const void* g, void* l) {
  __builtin_amdgcn_global_load_lds(
      (const __attribute__((address_space(1))) unsigned int*)g,
      (__attribute__((address_space(3))) unsigned int*)l, 16, 0, 0);
}

// ---------------- K1: gating + x->bf16 + scatter (fused) ---------------------
__global__ __launch_bounds__(256) void gating_kernel(
    const float* __restrict__ x, const float* __restrict__ gate_w,
    unsigned short* __restrict__ xh,
    float* __restrict__ topk_w, int* __restrict__ cursors,
    int* __restrict__ tok_list) {
  __shared__ float xr[H_DIM];
  __shared__ float logits[E_NUM];
  int t = blockIdx.x;
  int tid = threadIdx.x;
  const float* xrow = x + (size_t)t * H_DIM;
  float4 v = *(const float4*)(xrow + tid * 4);
  *(float4*)(xr + tid * 4) = v;
  {
    float f[4] = {v.x, v.y, v.z, v.w};
    u16x4 hv;
    #pragma unroll
    for (int j = 0; j < 4; ++j) hv[j] = f2bf(f[j]);
    *(u16x4*)(xh + (size_t)t * H_DIM + tid * 4) = hv;
  }
  __syncthreads();
  int wave = tid >> 6, lane = tid & 63;
  const float4* x4 = (const float4*)xr;
  for (int e8 = 0; e8 < 8; ++e8) {
    int e = wave * 8 + e8;
    const float4* g4 = (const float4*)(gate_w + (size_t)e * H_DIM);
    float p = 0.f;
    #pragma unroll
    for (int i = 0; i < 4; ++i) {
      float4 a = x4[lane + i * 64];
      float4 b = g4[lane + i * 64];
      p += a.x * b.x + a.y * b.y + a.z * b.z + a.w * b.w;
    }
    for (int off = 32; off > 0; off >>= 1) p += __shfl_down(p, off, 64);
    if (lane == 0) logits[e] = p;
  }
  __syncthreads();
  if (tid == 0) {
    float vv[E_NUM];
    for (int e = 0; e < E_NUM; ++e) vv[e] = logits[e];
    int ids[TOPK]; float vals[TOPK];
    for (int k = 0; k < TOPK; ++k) {
      int bi = 0; float bv = -1e30f;
      for (int e = 0; e < E_NUM; ++e) if (vv[e] > bv) { bv = vv[e]; bi = e; }
      ids[k] = bi; vals[k] = bv; vv[bi] = -1e30f;
    }
    float m = vals[0];
    float w[TOPK]; float s = 0.f;
    for (int k = 0; k < TOPK; ++k) { w[k] = expf(vals[k] - m); s += w[k]; }
    float inv = 1.f / s;
    for (int k = 0; k < TOPK; ++k) {
      int g = t * TOPK + k;
      topk_w[g] = w[k] * inv;
      int slot = atomicAdd(&cursors[ids[k]], 1);
      tok_list[ids[k] * T_TOK + slot] = g;
    }
  }
}

// ---------------- K2: tile list (256-row tiles) ------------------------------
__global__ void build_tiles(const int* __restrict__ cursors,
                            int* __restrict__ n_tiles, int* __restrict__ tile_info) {
  int lane = threadIdx.x;  // 64
  int c = (lane < E_NUM) ? cursors[lane] : 0;
  int nt = (c + 255) >> 8;
  int pfx = nt;
  for (int off = 1; off < 64; off <<= 1) {
    int v = __shfl_up(pfx, off, 64);
    if (lane >= off) pfx += v;
  }
  if (lane == E_NUM - 1) n_tiles[0] = pfx;
  int excl = pfx - nt;
  if (lane < E_NUM)
    for (int i = 0; i < nt; ++i) tile_info[excl + i] = (lane << 8) | i;
}

// ---------------- K2b: fill padded slot->pair map (all SLOTS, deterministic) -
__global__ __launch_bounds__(256) void fill_slots(
    const int* __restrict__ cursors, const int* __restrict__ n_tiles,
    const int* __restrict__ tile_info, const int* __restrict__ tok_list,
    int* __restrict__ slot_pair) {
  int b = blockIdx.x;  // 0..MAXT-1
  int tid = threadIdx.x;
  int pair = -1;
  if (b < n_tiles[0]) {
    int info = tile_info[b];
    int e = info >> 8, i = info & 255;
    int idx = i * 256 + tid;
    if (idx < cursors[e]) pair = tok_list[e * T_TOK + idx];
  }
  slot_pair[b * 256 + tid] = pair;
}

// ---------------- K3/K5: 256x256-tile grouped GEMM ---------------------------
// MODE 0: A = xh gathered by slot->token  [K=1024], B = concat(w_gate,w_up)
//         (N=1024/expert, fp32), C -> gu_raw bf16 [slot][1024].
// MODE 1: A = mixed (linear slots) [K=512], B = w_down (N=1024, fp32),
//         C -> atomicAdd out[token][1024].
// Geometry: 512 thr = 8 waves (2M x 4N); wave tile 128x64; BK=64.
// LDS: double buffer x (A 32KB + B 32KB) bf16.  One barrier per K-step:
//   syncthreads (vmcnt0: A-DMA(t) landed, B(t+1) regs in; lgkm drain)
//   -> ds_write B(t+1) to buf^1 -> issue A-DMA(t+1, buf^1) -> issue B(t+2)
//   -> compute buf[cur].
// Swizzle (r8-verified, conflicts==0): elem(row,k-octet ko) stored at ushort
//   row*64 + (ko ^ (row&7))*8.  A via DMA: linear LDS dest, pre-swizzled
//   per-lane GLOBAL source (rule #21).  B: swizzled ds_write.
template <int MODE>
__global__ __launch_bounds__(512, 2) void gemm256(
    const unsigned short* __restrict__ xh,
    const unsigned short* __restrict__ mixed,
    const float* __restrict__ w_gate, const float* __restrict__ w_up,
    const float* __restrict__ w_down,
    const int* __restrict__ n_tiles, const int* __restrict__ tile_info,
    const int* __restrict__ slot_pair,
    unsigned short* __restrict__ gu_raw, float* __restrict__ out) {
  constexpr int KT = (MODE == 0) ? H_DIM : M_DIM;
  constexpr int NKS = KT / 64;
  int tidx = blockIdx.y;
  if (tidx >= n_tiles[0]) return;
  int info = tile_info[tidx];
  int e = info >> 8;
  int n0 = blockIdx.x * 256;
  int slot0 = tidx * 256;
  int tid = threadIdx.x;
  int lane = tid & 63, wid = tid >> 6;

  __shared__ unsigned short L[2][32768];  // per buf: A [0,16384), B [16384,32768)
  __shared__ int sp[256];

  if (tid < 256) sp[tid] = slot_pair[slot0 + tid];
  __syncthreads();

  // A-DMA per-lane swizzled global sources (4 issues, 8 rows each)
  const unsigned short* asrc[4];
  #pragma unroll
  for (int i = 0; i < 4; ++i) {
    int row = wid * 32 + i * 8 + (lane >> 3);
    int oct = (lane & 7) ^ (row & 7);
    if (MODE == 0) {
      int pr = sp[row];
      int tok = (pr >= 0) ? (pr >> 2) : 0;
      asrc[i] = xh + (size_t)tok * H_DIM + oct * 8;
    } else {
      asrc[i] = mixed + (size_t)(slot0 + row) * M_DIM + oct * 8;
    }
  }

  // B source (fp32): 2 threads per N-row, 32 k each
  int brow = tid >> 1, bkh = (tid & 1) * 32;
  const float* bsrc;
  if (MODE == 0) {
    int n = n0 + brow;
    bsrc = (n < M_DIM ? w_gate + ((size_t)e * M_DIM + n) * H_DIM
                      : w_up + ((size_t)e * M_DIM + (n - M_DIM)) * H_DIM) + bkh;
  } else {
    bsrc = w_down + ((size_t)e * H_DIM + n0 + brow) * M_DIM + bkh;
  }
  int bwo[4];
  #pragma unroll
  for (int i = 0; i < 4; ++i)
    bwo[i] = 16384 + brow * 64 + ((((tid & 1) * 4 + i)) ^ (brow & 7)) * 8;

  int wm = wid >> 2, wn = wid & 3;
  f32x4 acc[8][4] = {};
  float fb[32];

#define G_LOADB(K0) { _Pragma("unroll") \
    for (int q = 0; q < 8; ++q) \
      *(float4*)(fb + q * 4) = *(const float4*)(bsrc + (K0) + q * 4); }

#define G_WRITEB(BB) { _Pragma("unroll") \
    for (int i = 0; i < 4; ++i) { \
      bf16x8 v; \
      _Pragma("unroll") \
      for (int j = 0; j < 8; ++j) v[j] = (__bf16)fb[i * 8 + j]; \
      *(bf16x8*)&L[BB][bwo[i]] = v; } }

#define G_DMA_A(BB, K0) { _Pragma("unroll") \
    for (int i = 0; i < 4; ++i) \
      gload16(asrc[i] + (K0), &L[BB][(wid * 32 + i * 8) * 64]); }

#define G_COMPUTE(BB) { _Pragma("unroll") \
    for (int kf = 0; kf < 2; ++kf) { \
      int kl = kf * 4 + (lane >> 4); \
      bf16x8 av[8], bv[4]; \
      _Pragma("unroll") \
      for (int mf = 0; mf < 8; ++mf) { \
        int ra = wm * 128 + mf * 16 + (lane & 15); \
        av[mf] = *(const bf16x8*)&L[BB][ra * 64 + (kl ^ (ra & 7)) * 8]; } \
      _Pragma("unroll") \
      for (int nf = 0; nf < 4; ++nf) { \
        int cb = wn * 64 + nf * 16 + (lane & 15); \
        bv[nf] = *(const bf16x8*)&L[BB][16384 + cb * 64 + (kl ^ (cb & 7)) * 8]; } \
      _Pragma("unroll") \
      for (int mf = 0; mf < 8; ++mf) \
        _Pragma("unroll") \
        for (int nf = 0; nf < 4; ++nf) \
          acc[mf][nf] = mfma16(av[mf], bv[nf], acc[mf][nf]); } }

  // prologue: buf0 <- A(0), B(0); B(1) -> regs
  G_LOADB(0);
  G_DMA_A(0, 0);
  asm volatile("s_waitcnt vmcnt(0)" ::: "memory");
  __syncthreads();
  G_WRITEB(0);
  G_LOADB(64);

  for (int t = 0; t < NKS; ++t) {
    const int cur = t & 1;
    asm volatile("s_waitcnt vmcnt(0)" ::: "memory");
    __syncthreads();  // A(t) landed; B(t+1) regs in; buf writes visible; prev reads done
    if (t + 1 < NKS) {
      G_WRITEB(cur ^ 1);
      G_DMA_A(cur ^ 1, (t + 1) * 64);
    }
    if (t + 2 < NKS) G_LOADB((t + 2) * 64);
    G_COMPUTE(cur);
  }

  if (MODE == 0) {
    #pragma unroll
    for (int mf = 0; mf < 8; ++mf)
      #pragma unroll
      for (int j = 0; j < 4; ++j) {
        int row = wm * 128 + mf * 16 + (lane >> 4) * 4 + j;
        size_t rb = (size_t)(slot0 + row) * 1024 + n0 + wn * 64 + (lane & 15);
        #pragma unroll
        for (int nf = 0; nf < 4; ++nf) {
          __bf16 v = (__bf16)acc[mf][nf][j];
          gu_raw[rb + nf * 16] = *(unsigned short*)&v;
        }
      }
  } else {
    #pragma unroll
    for (int mf = 0; mf < 8; ++mf)
      #pragma unroll
      for (int j = 0; j < 4; ++j) {
        int row = wm * 128 + mf * 16 + (lane >> 4) * 4 + j;
        int pr = sp[row];
        if (pr < 0) continue;
        size_t ob = (size_t)(pr >> 2) * H_DIM + n0 + wn * 64 + (lane & 15);
        #pragma unroll
        for (int nf = 0; nf < 4; ++nf)
          atomicAdd(&out[ob + nf * 16], acc[mf][nf][j]);
      }
  }
}

// ---------------- K4: silu(g)*u*routew -> mixed (bf16) -----------------------
__global__ __launch_bounds__(256) void silu_kernel(
    const unsigned short* __restrict__ gu, const int* __restrict__ slot_pair,
    const float* __restrict__ topk_w, unsigned short* __restrict__ mixed) {
  int tid = threadIdx.x;
  int slot = blockIdx.x * 4 + (tid >> 6);
  int col = (tid & 63) * 8;
  int pr = slot_pair[slot];
  if (pr < 0) return;
  float w = topk_w[pr];
  const unsigned short* gp = gu + (size_t)slot * 1024 + col;
  u16x8 gg = *(const u16x8*)gp;
  u16x8 uu = *(const u16x8*)(gp + 512);
  bf16x8 o;
  #pragma unroll
  for (int j = 0; j < 8; ++j) {
    float g = __uint_as_float(((unsigned)gg[j]) << 16);
    float u = __uint_as_float(((unsigned)uu[j]) << 16);
    float v = (g / (1.f + __expf(-g))) * u * w;
    o[j] = (__bf16)v;
  }
  *(bf16x8*)(mixed + (size_t)slot * 512 + col) = o;
}

extern "C" void kernel_launch(void* const* d_in, const int* in_sizes, int n_in,
                              void* d_out, int out_size, void* d_ws, size_t ws_size,
                              hipStream_t stream) {
  const float* x      = (const float*)d_in[0];
  const float* gate_w = (const float*)d_in[1];
  const float* w_gate = (const float*)d_in[2];
  const float* w_up   = (const float*)d_in[3];
  const float* w_down = (const float*)d_in[4];
  float* out = (float*)d_out;

  char* ws = (char*)d_ws;
  size_t off = 0;
  float* topk_w    = (float*)(ws + off); off += (size_t)T_TOK * TOPK * 4;
  int*   cursors   = (int*)(ws + off);   off += 256;
  int*   n_tiles   = (int*)(ws + off);   off += 64;
  int*   tile_info = (int*)(ws + off);   off += MAXT * 4 + 64;
  int*   slot_pair = (int*)(ws + off);   off += (size_t)SLOTS * 4;
  int*   tok_list  = (int*)(ws + off);   off += (size_t)E_NUM * T_TOK * 4;
  unsigned short* x_hi   = (unsigned short*)(ws + off); off += (size_t)T_TOK * H_DIM * 2;
  unsigned short* gu_raw = (unsigned short*)(ws + off); off += (size_t)SLOTS * 1024 * 2;
  unsigned short* mixed  = (unsigned short*)(ws + off); off += (size_t)SLOTS * 512 * 2;

  hipMemsetAsync(cursors, 0, E_NUM * sizeof(int), stream);
  hipMemsetAsync(out, 0, (size_t)T_TOK * H_DIM * sizeof(float), stream);

  gating_kernel<<<T_TOK, 256, 0, stream>>>(x, gate_w, x_hi, topk_w,
                                           cursors, tok_list);
  build_tiles<<<1, 64, 0, stream>>>(cursors, n_tiles, tile_info);
  fill_slots<<<MAXT, 256, 0, stream>>>(cursors, n_tiles, tile_info, tok_list,
                                       slot_pair);
  gemm256<0><<<dim3(4, MAXT), 512, 0, stream>>>(
      x_hi, mixed, w_gate, w_up, w_down, n_tiles, tile_info, slot_pair,
      gu_raw, out);
  silu_kernel<<<SLOTS / 4, 256, 0, stream>>>(gu_raw, slot_pair, topk_w, mixed);
  gemm256<1><<<dim3(4, MAXT), 512, 0, stream>>>(
      x_hi, mixed, w_gate, w_up, w_down, n_tiles, tile_info, slot_pair,
      gu_raw, out);
}

// Round 11
// 199.136 us; speedup vs baseline: 1.0095x; 1.0095x over previous
//
#include <hip/hip_runtime.h>
#include <math.h>

#define T_TOK 2048
#define H_DIM 1024
#define M_DIM 512
#define E_NUM 32
#define TOPK  4

#define MAXT  63            // sum ceil(cnt/256) <= 31 + 8192/256 = 63
#define SLOTS (MAXT * 256)  // 16128 padded pair-slots

typedef __bf16 bf16x8 __attribute__((ext_vector_type(8)));
typedef float f32x4 __attribute__((ext_vector_type(4)));
typedef unsigned short u16x8 __attribute__((ext_vector_type(8)));
typedef unsigned short u16x4 __attribute__((ext_vector_type(4)));

__device__ __forceinline__ unsigned short f2bf(float f) {
  unsigned u = __float_as_uint(f);
  return (unsigned short)((u + 0x7fffu + ((u >> 16) & 1u)) >> 16);
}
__device__ __forceinline__ f32x4 mfma16(bf16x8 a, bf16x8 b, f32x4 c) {
  return __builtin_amdgcn_mfma_f32_16x16x32_bf16(a, b, c, 0, 0, 0);
}
__device__ __forceinline__ void gload16(const void* g, void* l) {
  __builtin_amdgcn_global_load_lds(
      (const __attribute__((address_space(1))) unsigned int*)g,
      (__attribute__((address_space(3))) unsigned int*)l, 16, 0, 0);
}
__device__ __forceinline__ bf16x8 cvt8(f32x4 a, f32x4 b) {
  bf16x8 r;
  #pragma unroll
  for (int j = 0; j < 4; ++j) { r[j] = (__bf16)a[j]; r[4 + j] = (__bf16)b[j]; }
  return r;
}

// ---------------- K1: gating + x->bf16 + scatter (fused) ---------------------
__global__ __launch_bounds__(256) void gating_kernel(
    const float* __restrict__ x, const float* __restrict__ gate_w,
    unsigned short* __restrict__ xh,
    float* __restrict__ topk_w, int* __restrict__ cursors,
    int* __restrict__ tok_list) {
  __shared__ float xr[H_DIM];
  __shared__ float logits[E_NUM];
  int t = blockIdx.x;
  int tid = threadIdx.x;
  const float* xrow = x + (size_t)t * H_DIM;
  float4 v = *(const float4*)(xrow + tid * 4);
  *(float4*)(xr + tid * 4) = v;
  {
    float f[4] = {v.x, v.y, v.z, v.w};
    u16x4 hv;
    #pragma unroll
    for (int j = 0; j < 4; ++j) hv[j] = f2bf(f[j]);
    *(u16x4*)(xh + (size_t)t * H_DIM + tid * 4) = hv;
  }
  __syncthreads();
  int wave = tid >> 6, lane = tid & 63;
  const float4* x4 = (const float4*)xr;
  for (int e8 = 0; e8 < 8; ++e8) {
    int e = wave * 8 + e8;
    const float4* g4 = (const float4*)(gate_w + (size_t)e * H_DIM);
    float p = 0.f;
    #pragma unroll
    for (int i = 0; i < 4; ++i) {
      float4 a = x4[lane + i * 64];
      float4 b = g4[lane + i * 64];
      p += a.x * b.x + a.y * b.y + a.z * b.z + a.w * b.w;
    }
    for (int off = 32; off > 0; off >>= 1) p += __shfl_down(p, off, 64);
    if (lane == 0) logits[e] = p;
  }
  __syncthreads();
  if (tid == 0) {
    float vv[E_NUM];
    for (int e = 0; e < E_NUM; ++e) vv[e] = logits[e];
    int ids[TOPK]; float vals[TOPK];
    for (int k = 0; k < TOPK; ++k) {
      int bi = 0; float bv = -1e30f;
      for (int e = 0; e < E_NUM; ++e) if (vv[e] > bv) { bv = vv[e]; bi = e; }
      ids[k] = bi; vals[k] = bv; vv[bi] = -1e30f;
    }
    float m = vals[0];
    float w[TOPK]; float s = 0.f;
    for (int k = 0; k < TOPK; ++k) { w[k] = expf(vals[k] - m); s += w[k]; }
    float inv = 1.f / s;
    for (int k = 0; k < TOPK; ++k) {
      int g = t * TOPK + k;
      topk_w[g] = w[k] * inv;
      int slot = atomicAdd(&cursors[ids[k]], 1);
      tok_list[ids[k] * T_TOK + slot] = g;
    }
  }
}

// ---------------- K2: tile list (256-row tiles) ------------------------------
__global__ void build_tiles(const int* __restrict__ cursors,
                            int* __restrict__ n_tiles, int* __restrict__ tile_info) {
  int lane = threadIdx.x;  // 64
  int c = (lane < E_NUM) ? cursors[lane] : 0;
  int nt = (c + 255) >> 8;
  int pfx = nt;
  for (int off = 1; off < 64; off <<= 1) {
    int v = __shfl_up(pfx, off, 64);
    if (lane >= off) pfx += v;
  }
  if (lane == E_NUM - 1) n_tiles[0] = pfx;
  int excl = pfx - nt;
  if (lane < E_NUM)
    for (int i = 0; i < nt; ++i) tile_info[excl + i] = (lane << 8) | i;
}

// ---------------- K2b: fill padded slot->pair map ----------------------------
__global__ __launch_bounds__(256) void fill_slots(
    const int* __restrict__ cursors, const int* __restrict__ n_tiles,
    const int* __restrict__ tile_info, const int* __restrict__ tok_list,
    int* __restrict__ slot_pair) {
  int b = blockIdx.x;
  int tid = threadIdx.x;
  int pair = -1;
  if (b < n_tiles[0]) {
    int info = tile_info[b];
    int e = info >> 8, i = info & 255;
    int idx = i * 256 + tid;
    if (idx < cursors[e]) pair = tok_list[e * T_TOK + idx];
  }
  slot_pair[b * 256 + tid] = pair;
}

// ---------------- K3/K5: 256x256 grouped GEMM, 3-buf DMA counted-vmcnt -------
// All staging via global_load_lds (no VGPR round trip; exact vmcnt counts).
// Per K-step (BK=32): A 16KB bf16 (1024 chunks) + B 32KB fp32 (2048 chunks).
// Chunk->elem bijections (conflict-<=2-way on both reads, derived & checked):
//  A: chunk (blk*64+l), blk=wid*2+i: row=blk*16+(l>>2), oct=((l&3)-((l>>2)>>1))&3
//     read: ushort idx (row>>4)*512 + (row&15)*32 + ((oct+((row&15)>>1))&3)*8
//  B: chunk (ci*64+l), ci=wid*4+i: blk=ci>>1, w7=((ci&1)<<6)+l,
//     col=blk*16+(w7>>3), q=((w7&7)-((w7>>3)&7))&7  (q = 4-float group of 8)
//     read: float idx (col>>4)*512 + (col&15)*32 + ((q+(col&7))&7)*4
// Pipeline: STAGE(t+2) -> vmcnt(12) [t landed; t+1,t+2 in flight] -> barrier
//   -> COMPUTE(t%3) -> lgkmcnt(0) -> barrier.  HBM never drains.
template <int MODE>
__global__ __launch_bounds__(512, 2) void gemm256(
    const unsigned short* __restrict__ xh,
    const unsigned short* __restrict__ mixed,
    const float* __restrict__ w_gate, const float* __restrict__ w_up,
    const float* __restrict__ w_down,
    const int* __restrict__ n_tiles, const int* __restrict__ tile_info,
    const int* __restrict__ slot_pair,
    unsigned short* __restrict__ gu_raw, float* __restrict__ out) {
  constexpr int KT = (MODE == 0) ? H_DIM : M_DIM;
  constexpr int NKS = KT / 32;
  int tidx = blockIdx.y;
  if (tidx >= n_tiles[0]) return;
  int info = tile_info[tidx];
  int e = info >> 8;
  int n0 = blockIdx.x * 256;
  int slot0 = tidx * 256;
  int tid = threadIdx.x;
  int lane = tid & 63, wid = tid >> 6;

  __shared__ unsigned short L[3][24576];  // per buf 48KB: A ushort[0,8192), B f32 [8192,24576)
  __shared__ int sp[256];

  if (tid < 256) sp[tid] = slot_pair[slot0 + tid];
  __syncthreads();

  // A DMA sources (2 issues/thread)
  const unsigned short* asrc0;
  const unsigned short* asrc1;
  {
    #pragma unroll
    for (int i = 0; i < 2; ++i) {
      int blk = wid * 2 + i;
      int row = blk * 16 + (lane >> 2);
      int oct = ((lane & 3) - ((lane >> 2) >> 1)) & 3;
      const unsigned short* s;
      if (MODE == 0) {
        int pr = sp[row];
        int tok = (pr >= 0) ? (pr >> 2) : 0;
        s = xh + (size_t)tok * H_DIM + oct * 8;
      } else {
        s = mixed + (size_t)(slot0 + row) * M_DIM + oct * 8;
      }
      if (i == 0) asrc0 = s; else asrc1 = s;
    }
  }
  // B DMA sources (4 issues/thread)
  const float* bsrc0; const float* bsrc1; const float* bsrc2; const float* bsrc3;
  {
    #pragma unroll
    for (int i = 0; i < 4; ++i) {
      int ci = wid * 4 + i;
      int blk = ci >> 1;
      int w7 = ((ci & 1) << 6) + lane;
      int col = blk * 16 + (w7 >> 3);
      int q = ((w7 & 7) - ((w7 >> 3) & 7)) & 7;
      const float* base;
      if (MODE == 0) {
        int n = n0 + col;
        base = (n < M_DIM) ? w_gate + ((size_t)e * M_DIM + n) * H_DIM
                           : w_up + ((size_t)e * M_DIM + (n - M_DIM)) * H_DIM;
      } else {
        base = w_down + ((size_t)e * H_DIM + n0 + col) * M_DIM;
      }
      base += q * 4;
      if (i == 0) bsrc0 = base; else if (i == 1) bsrc1 = base;
      else if (i == 2) bsrc2 = base; else bsrc3 = base;
    }
  }

  int wm = wid >> 2, wn = wid & 3;
  int l15 = lane & 15, o4 = lane >> 4, l7 = lane & 7;
  f32x4 acc[8][4] = {};

#define STAGE(P, KS) { \
    gload16(asrc0 + (KS) * 32, &L[P][(wid * 2 + 0) * 512]); \
    gload16(asrc1 + (KS) * 32, &L[P][(wid * 2 + 1) * 512]); \
    gload16(bsrc0 + (KS) * 32, &L[P][8192 + (wid * 4 + 0) * 512]); \
    gload16(bsrc1 + (KS) * 32, &L[P][8192 + (wid * 4 + 1) * 512]); \
    gload16(bsrc2 + (KS) * 32, &L[P][8192 + (wid * 4 + 2) * 512]); \
    gload16(bsrc3 + (KS) * 32, &L[P][8192 + (wid * 4 + 3) * 512]); }

#define COMPUTE(P) { \
    const unsigned short* Ab = &L[P][0]; \
    const float* Bb = (const float*)&L[P][8192]; \
    bf16x8 av[8]; bf16x8 bv[4]; \
    _Pragma("unroll") \
    for (int mf = 0; mf < 8; ++mf) { \
      int idx = (wm * 8 + mf) * 512 + l15 * 32 + ((o4 + (l15 >> 1)) & 3) * 8; \
      av[mf] = *(const bf16x8*)&Ab[idx]; } \
    _Pragma("unroll") \
    for (int nf = 0; nf < 4; ++nf) { \
      int b0 = (wn * 4 + nf) * 512 + l15 * 32 + ((2 * o4 + l7) & 7) * 4; \
      int b1 = (wn * 4 + nf) * 512 + l15 * 32 + ((2 * o4 + 1 + l7) & 7) * 4; \
      bv[nf] = cvt8(*(const f32x4*)&Bb[b0], *(const f32x4*)&Bb[b1]); } \
    _Pragma("unroll") \
    for (int mf = 0; mf < 8; ++mf) \
      _Pragma("unroll") \
      for (int nf = 0; nf < 4; ++nf) \
        acc[mf][nf] = mfma16(av[mf], bv[nf], acc[mf][nf]); }

  // prologue: 2 steps in flight
  STAGE(0, 0);
  STAGE(1, 1);
  for (int t = 0; t < NKS; ++t) {
    int p = t % 3;
    if (t + 2 < NKS) {
      STAGE((t + 2) % 3, t + 2);
      asm volatile("s_waitcnt vmcnt(12)" ::: "memory");  // step t landed; 12 fly on
    } else if (t + 1 < NKS) {
      asm volatile("s_waitcnt vmcnt(6)" ::: "memory");
    } else {
      asm volatile("s_waitcnt vmcnt(0)" ::: "memory");
    }
    __builtin_amdgcn_s_barrier();          // all waves' stage(t) visible
    __builtin_amdgcn_sched_barrier(0);
    COMPUTE(p);
    asm volatile("s_waitcnt lgkmcnt(0)" ::: "memory");
    __builtin_amdgcn_s_barrier();          // all reads of buf p done before overwrite
  }

  if (MODE == 0) {
    #pragma unroll
    for (int mf = 0; mf < 8; ++mf)
      #pragma unroll
      for (int j = 0; j < 4; ++j) {
        int row = wm * 128 + mf * 16 + (lane >> 4) * 4 + j;
        size_t rb = (size_t)(slot0 + row) * 1024 + n0 + wn * 64 + (lane & 15);
        #pragma unroll
        for (int nf = 0; nf < 4; ++nf) {
          __bf16 v = (__bf16)acc[mf][nf][j];
          gu_raw[rb + nf * 16] = *(unsigned short*)&v;
        }
      }
  } else {
    #pragma unroll
    for (int mf = 0; mf < 8; ++mf)
      #pragma unroll
      for (int j = 0; j < 4; ++j) {
        int row = wm * 128 + mf * 16 + (lane >> 4) * 4 + j;
        int pr = sp[row];
        if (pr < 0) continue;
        size_t ob = (size_t)(pr >> 2) * H_DIM + n0 + wn * 64 + (lane & 15);
        #pragma unroll
        for (int nf = 0; nf < 4; ++nf)
          atomicAdd(&out[ob + nf * 16], acc[mf][nf][j]);
      }
  }
}

// ---------------- K4: silu(g)*u*routew -> mixed (bf16) -----------------------
__global__ __launch_bounds__(256) void silu_kernel(
    const unsigned short* __restrict__ gu, const int* __restrict__ slot_pair,
    const float* __restrict__ topk_w, unsigned short* __restrict__ mixed) {
  int tid = threadIdx.x;
  int slot = blockIdx.x * 4 + (tid >> 6);
  int col = (tid & 63) * 8;
  int pr = slot_pair[slot];
  if (pr < 0) return;
  float w = topk_w[pr];
  const unsigned short* gp = gu + (size_t)slot * 1024 + col;
  u16x8 gg = *(const u16x8*)gp;
  u16x8 uu = *(const u16x8*)(gp + 512);
  bf16x8 o;
  #pragma unroll
  for (int j = 0; j < 8; ++j) {
    float g = __uint_as_float(((unsigned)gg[j]) << 16);
    float u = __uint_as_float(((unsigned)uu[j]) << 16);
    float v = (g / (1.f + __expf(-g))) * u * w;
    o[j] = (__bf16)v;
  }
  *(bf16x8*)(mixed + (size_t)slot * 512 + col) = o;
}

extern "C" void kernel_launch(void* const* d_in, const int* in_sizes, int n_in,
                              void* d_out, int out_size, void* d_ws, size_t ws_size,
                              hipStream_t stream) {
  const float* x      = (const float*)d_in[0];
  const float* gate_w = (const float*)d_in[1];
  const float* w_gate = (const float*)d_in[2];
  const float* w_up   = (const float*)d_in[3];
  const float* w_down = (const float*)d_in[4];
  float* out = (float*)d_out;

  char* ws = (char*)d_ws;
  size_t off = 0;
  float* topk_w    = (float*)(ws + off); off += (size_t)T_TOK * TOPK * 4;
  int*   cursors   = (int*)(ws + off);   off += 256;
  int*   n_tiles   = (int*)(ws + off);   off += 64;
  int*   tile_info = (int*)(ws + off);   off += MAXT * 4 + 64;
  int*   slot_pair = (int*)(ws + off);   off += (size_t)SLOTS * 4;
  int*   tok_list  = (int*)(ws + off);   off += (size_t)E_NUM * T_TOK * 4;
  unsigned short* x_hi   = (unsigned short*)(ws + off); off += (size_t)T_TOK * H_DIM * 2;
  unsigned short* gu_raw = (unsigned short*)(ws + off); off += (size_t)SLOTS * 1024 * 2;
  unsigned short* mixed  = (unsigned short*)(ws + off); off += (size_t)SLOTS * 512 * 2;

  hipMemsetAsync(cursors, 0, E_NUM * sizeof(int), stream);
  hipMemsetAsync(out, 0, (size_t)T_TOK * H_DIM * sizeof(float), stream);

  gating_kernel<<<T_TOK, 256, 0, stream>>>(x, gate_w, x_hi, topk_w,
                                           cursors, tok_list);
  build_tiles<<<1, 64, 0, stream>>>(cursors, n_tiles, tile_info);
  fill_slots<<<MAXT, 256, 0, stream>>>(cursors, n_tiles, tile_info, tok_list,
                                       slot_pair);
  gemm256<0><<<dim3(4, MAXT), 512, 0, stream>>>(
      x_hi, mixed, w_gate, w_up, w_down, n_tiles, tile_info, slot_pair,
      gu_raw, out);
  silu_kernel<<<SLOTS / 4, 256, 0, stream>>>(gu_raw, slot_pair, topk_w, mixed);
  gemm256<1><<<dim3(4, MAXT), 512, 0, stream>>>(
      x_hi, mixed, w_gate, w_up, w_down, n_tiles, tile_info, slot_pair,
      gu_raw, out);
}